// Round 8
// baseline (106.079 us; speedup 1.0000x reference)
//
#include <hip/hip_runtime.h>
#include <math.h>

#define Bsz 2048
#define Ddim 32
#define Nsz 8192
#define Kk 30
#define TPB 256
#define RG (Bsz / TPB)     // 8 row-groups
#define JS 64              // j slices
#define JT (Bsz / JS)      // 32 j per block

// Lane owns row i: zi (32 VGPR) and the row's 30 knn ids (30 VGPR) are
// PRIVATE per-lane data -> no hoist/spill hazard (R4/R6 trap was shared
// block-uniform data ballooning into per-lane registers). j-tile staged in
// LDS; per-j reads are uniform broadcasts that VARY with the loop index (no
// invariant-hoist). Mask = 30-step xor/min chain vs uniform sj (no bitset,
// no M matrix, no mask kernel). One fused kernel + 16 KB memset: den/num
// accumulate via per-lane atomicAdd, counter + last-block finalize (R2
// pattern, proven) computes the scalar loss in-kernel.
__global__ __launch_bounds__(TPB, 2) void softnp_main(
    const float* __restrict__ z,
    const int*   __restrict__ pre_knn,
    const int*   __restrict__ samp,
    float*       __restrict__ gden,   // [Bsz] zero-init by memset
    float*       __restrict__ gnum,   // [Bsz] zero-init by memset
    unsigned*    __restrict__ ctr,    // zero-init by memset
    float*       __restrict__ out)
{
    __shared__ float    zjt[JT * Ddim];   // 4 KB j-tile
    __shared__ float    sqj[JT];
    __shared__ int      sjs[JT];
    __shared__ float    rl[4], rc[4];
    __shared__ unsigned amlast;

    const int t   = threadIdx.x;
    const int rg  = blockIdx.x >> 6;        // row-group (8)
    const int js  = blockIdx.x & (JS - 1);  // j-slice (64)
    const int row = rg * TPB + t;
    const int j0  = js * JT;

    // ---- own-row private data (issued before barriers for overlap) ----
    float4 zi[8];
    const float4* zr = (const float4*)(z + (size_t)row * Ddim);
    #pragma unroll
    for (int d = 0; d < 8; ++d) zi[d] = zr[d];
    const int sr = samp[row];
    int ids[Kk];
    const int* ib = pre_knn + (size_t)sr * Kk;
    #pragma unroll
    for (int k = 0; k < Kk; ++k) ids[k] = ib[k];

    float si2 = 0.f;
    #pragma unroll
    for (int d = 0; d < 8; ++d)
        si2 += zi[d].x * zi[d].x + zi[d].y * zi[d].y
             + zi[d].z * zi[d].z + zi[d].w * zi[d].w;

    // ---- stage j-tile: 32 rows x 128 B = 256 float4, one per thread ----
    ((float4*)zjt)[t] = ((const float4*)z)[(size_t)j0 * 8 + t];
    if (t < JT) sjs[t] = samp[j0 + t];
    __syncthreads();
    if (t < JT) {
        const float4* a = (const float4*)(zjt + t * Ddim);
        float s = 0.f;
        #pragma unroll
        for (int d = 0; d < 8; ++d)
            s += a[d].x * a[d].x + a[d].y * a[d].y
               + a[d].z * a[d].z + a[d].w * a[d].w;
        sqj[t] = s;
    }
    __syncthreads();

    // ---- hot loop: 32 uniform j's vs my row ----
    float den = 0.f, num = 0.f;
    for (int c = 0; c < JT; ++c) {
        const float4* v4 = (const float4*)(zjt + c * Ddim); // varies with c
        float dot = 0.f;
        #pragma unroll
        for (int d = 0; d < 8; ++d) {
            const float4 v = v4[d];   // uniform-address LDS broadcast
            dot += zi[d].x * v.x + zi[d].y * v.y + zi[d].z * v.z + zi[d].w * v.w;
        }
        const float d2 = fmaxf(si2 + sqj[c] - 2.f * dot, 0.f);
        const float e  = (j0 + c == row) ? 0.f : __expf(-sqrtf(d2));
        den += e;
        const unsigned sj = (unsigned)sjs[c];
        unsigned mn = 0xFFFFFFFFu;            // min over (sj ^ id): 0 iff match
        #pragma unroll
        for (int k = 0; k < Kk; ++k) mn = min(mn, sj ^ (unsigned)ids[k]);
        num += (mn == 0u) ? e : 0.f;
    }

    atomicAdd(&gden[row], den);
    atomicAdd(&gnum[row], num);

    // ---- counter + last-block finalize (R2-proven pattern) ----
    __threadfence();
    __syncthreads();
    if (t == 0)
        amlast = (atomicAdd(ctr, 1u) == (unsigned)gridDim.x - 1u) ? 1u : 0u;
    __syncthreads();
    if (amlast) {
        __threadfence();
        float loss = 0.f, cnt = 0.f;
        #pragma unroll
        for (int c = 0; c < RG; ++c) {
            const int r = c * TPB + t;
            const float D  = atomicAdd(&gden[r], 0.0f);   // coherent read
            const float Nm = atomicAdd(&gnum[r], 0.0f);
            if (Nm > 0.f) {          // valid <=> any masked neighbor
                loss -= __logf(Nm / D + 1e-8f);
                cnt  += 1.f;
            }
        }
        #pragma unroll
        for (int off = 32; off > 0; off >>= 1) {
            loss += __shfl_xor(loss, off, 64);
            cnt  += __shfl_xor(cnt,  off, 64);
        }
        const int lane = t & 63, wv = t >> 6;
        if (lane == 0) { rl[wv] = loss; rc[wv] = cnt; }
        __syncthreads();
        if (t == 0) {
            const float L = rl[0] + rl[1] + rl[2] + rl[3];
            const float C = rc[0] + rc[1] + rc[2] + rc[3];
            out[0] = (C > 0.f) ? L / C : 0.f;
        }
    }
}

extern "C" void kernel_launch(void* const* d_in, const int* in_sizes, int n_in,
                              void* d_out, int out_size, void* d_ws, size_t ws_size,
                              hipStream_t stream)
{
    const float* z       = (const float*)d_in[0];
    const int*   pre_knn = (const int*)d_in[1];
    const int*   samp    = (const int*)d_in[2];
    float*       out     = (float*)d_out;

    float*    gden = (float*)d_ws;            // [2048]
    float*    gnum = gden + Bsz;              // [2048]
    unsigned* ctr  = (unsigned*)(gnum + Bsz); // [1]

    // zero den/num accumulators + done-counter (16388 B, ~1 us)
    hipMemsetAsync(d_ws, 0, (size_t)(2 * Bsz) * sizeof(float) + sizeof(unsigned),
                   stream);

    softnp_main<<<dim3(RG * JS), dim3(TPB), 0, stream>>>(
        z, pre_knn, samp, gden, gnum, ctr, out);
}